// Round 15
// baseline (56.853 us; speedup 1.0000x reference)
//
#include <hip/hip_runtime.h>
#include <hip/hip_bf16.h>

#define BATCH 4
#define SEQ   4096
#define DIN   768
#define DOUT  64

typedef __attribute__((ext_vector_type(4))) float f32x4;
typedef __attribute__((ext_vector_type(8))) short short8;
typedef __attribute__((ext_vector_type(4))) short short4v;

#define QSCALE 0.18033688011112043f  /* 0.125 * log2(e) */

static __device__ __forceinline__ unsigned short f2bf(float f) {
    union { float f; unsigned u; } un; un.f = f;
    unsigned r = un.u + 0x7FFF + ((un.u >> 16) & 1);
    return (unsigned short)(r >> 16);
}
static __device__ __forceinline__ float bf2f(unsigned short h) {
    union { unsigned u; float f; } un; un.u = ((unsigned)h) << 16;
    return un.f;
}

// ---------------------------------------------------------------------------
// Kernel 0 (v2, unchanged): weights -> B-fragment order.
// ---------------------------------------------------------------------------
__global__ void wprep_kernel(const float* __restrict__ wq,
                             const float* __restrict__ wk,
                             const float* __restrict__ wv,
                             unsigned short* __restrict__ wF) {
    __shared__ float lds[64][65];
    int o = blockIdx.x / 12, kt = blockIdx.x % 12;
    const float* w = (o == 0) ? wq : (o == 1) ? wk : wv;
    int tid = threadIdx.x;
    int k0 = kt * 64;
    #pragma unroll
    for (int i = 0; i < 16; ++i) {
        int flat = tid + i * 256;
        int kl = flat >> 6, n = flat & 63;
        lds[kl][n] = w[(k0 + kl) * 64 + n];
    }
    __syncthreads();
    int lane = tid & 63;
    int m = lane & 15, g = lane >> 4;
    #pragma unroll
    for (int i = 0; i < 2; ++i) {
        int f = i * 4 + (tid >> 6);
        int t = f >> 1, kcl = f & 1;
        int kc = kt * 2 + kcl;
        int nc = o * 4 + t;
        short8 v;
        #pragma unroll
        for (int j = 0; j < 8; ++j)
            v[j] = (short)f2bf(lds[kcl * 32 + g * 8 + j][t * 16 + m]);
        *(short8*)&wF[(size_t)(nc * 24 + kc) * 512 + lane * 8] = v;
    }
}

// ---------------------------------------------------------------------------
// Kernel 1 (v8, unchanged): QKV projection, fragment-order I/O, 32 rows/blk.
// ---------------------------------------------------------------------------
__global__ void __launch_bounds__(256) proj_kernel(
        const float* __restrict__ x,
        const float* __restrict__ bq,
        const float* __restrict__ bk,
        const float* __restrict__ bv,
        const unsigned short* __restrict__ wF,
        unsigned short* __restrict__ Qf,
        unsigned short* __restrict__ Kf,
        unsigned short* __restrict__ Vf) {
    __shared__ __align__(16) unsigned short xs[32][776];   // 48.5 KB
    __shared__ unsigned short tr[4][16][24];               // 3 KB

    int tid = threadIdx.x;
    int w = tid >> 6;
    int lane = tid & 63;
    int m = lane & 15, g = lane >> 4;
    int r0 = blockIdx.x * 32;

    {
        const float* xbase = x + (size_t)r0 * DIN;
        #pragma unroll
        for (int i = 0; i < 24; ++i) {
            int flat4 = tid + i * 256;
            int row = flat4 / 192;
            int c4 = flat4 - row * 192;
            float4 v = *(const float4*)(xbase + (size_t)row * DIN + c4 * 4);
            short4v sv;
            sv[0] = (short)f2bf(v.x); sv[1] = (short)f2bf(v.y);
            sv[2] = (short)f2bf(v.z); sv[3] = (short)f2bf(v.w);
            *(short4v*)&xs[row][c4 * 4] = sv;
        }
    }
    __syncthreads();

    f32x4 acc[2][3];
    #pragma unroll
    for (int st = 0; st < 2; ++st)
        #pragma unroll
        for (int t = 0; t < 3; ++t) acc[st][t] = (f32x4){0.f, 0.f, 0.f, 0.f};

    for (int kc = 0; kc < 24; ++kc) {
        short8 af0 = *(const short8*)&xs[m][kc * 32 + g * 8];
        short8 af1 = *(const short8*)&xs[16 + m][kc * 32 + g * 8];
        #pragma unroll
        for (int tt = 0; tt < 3; ++tt) {
            int nc = w * 3 + tt;
            short8 bfrg = *(const short8*)(wF + (size_t)(nc * 24 + kc) * 512 + lane * 8);
            acc[0][tt] = __builtin_amdgcn_mfma_f32_16x16x32_bf16(af0, bfrg, acc[0][tt], 0, 0, 0);
            acc[1][tt] = __builtin_amdgcn_mfma_f32_16x16x32_bf16(af1, bfrg, acc[1][tt], 0, 0, 0);
        }
    }

    int b2 = r0 >> 12;
    int s = (r0 & 4095) >> 5;
    #pragma unroll
    for (int st = 0; st < 2; ++st) {
        #pragma unroll
        for (int tt = 0; tt < 3; ++tt) {
            int nc = w * 3 + tt;
            int o = nc >> 2;
            int t = nc & 3;
            const float* bias_p = (o == 0) ? bq : (o == 1) ? bk : bv;
            float bias = bias_p[t * 16 + m];
            #pragma unroll
            for (int r = 0; r < 4; ++r) {
                float val = acc[st][tt][r] + bias;
                if (o == 0) val *= QSCALE;
                tr[w][g * 4 + r][m] = f2bf(val);
            }
            if (o < 2) {
                if (g < 2) {
                    short8 v8;
                    #pragma unroll
                    for (int j = 0; j < 8; ++j) v8[j] = (short)tr[w][m][g * 8 + j];
                    unsigned short* dst = (o == 0) ? Qf : Kf;
                    int c = t >> 1;
                    *(short8*)&dst[(size_t)((blockIdx.x * 2 + st) * 2 + c) * 512
                                   + (((t & 1) * 2 + g) * 16 + m) * 8] = v8;
                }
            } else {
                if (g < 2) {
                    short8 v8;
                    #pragma unroll
                    for (int j = 0; j < 8; ++j) v8[j] = (short)tr[w][g * 8 + j][m];
                    *(short8*)&Vf[((size_t)(b2 * 128 + s) * 4 + t) * 512
                                  + ((st * 2 + g) * 16 + m) * 8] = v8;
                }
            }
        }
    }
}

// ---------------------------------------------------------------------------
// Kernel 2 (v9): round-14 structure (complementary q-tile pairing) +
// EXPLICIT K/V SOFTWARE PIPELINE under __launch_bounds__(512, 1).
// Round-11's pipeline failed because (512,4) capped VGPR at 64 -> 100dw/thr
// scratch spill. Round 12-14's (512,2/4) without a pipeline left the 8 L2
// loads serialized (chain ~6000cy -> 1500cy/iter at 4-way TLP). Here:
// state ~110 VGPR + 64 prefetch regs fits the (512,1) budget with no spill;
// loads for s+8 issue before the compute of s -> chain ~1500cy pipelined.
// Trade: 1 block/CU (2 waves/SIMD) -- betting ILP > lost TLP.
// ---------------------------------------------------------------------------
__global__ void __launch_bounds__(512, 1) attn_kernel(
        const unsigned short* __restrict__ Qf,
        const unsigned short* __restrict__ Kf,
        const unsigned short* __restrict__ Vf,
        float* __restrict__ out) {
    __shared__ __align__(16) unsigned short P_lds[8][32][36];
    __shared__ __align__(16) unsigned short pacc[8][16][68];
    __shared__ float pm[8][16];
    __shared__ float pl[8][16];

    int j = blockIdx.x;
    int b = j & 3;
    int qt = j >> 2;                       // 0..127
    int base0 = qt * 16;                   // shallow tile rows
    int base1 = (255 - qt) * 16;           // deep tile rows
    int ns0 = (qt + 2) >> 1;
    int ns1 = (257 - qt) >> 1;
    int tid = threadIdx.x;
    int w = tid >> 6;
    int lane = tid & 63;
    int m = lane & 15, g = lane >> 4;

    const unsigned short* Q0 = Qf + (size_t)(b * 256 + qt) * 1024 + lane * 8;
    const unsigned short* Q1 = Qf + (size_t)(b * 256 + 255 - qt) * 1024 + lane * 8;
    short8 qf[2][2];
    qf[0][0] = *(const short8*)(Q0);
    qf[0][1] = *(const short8*)(Q0 + 512);
    qf[1][0] = *(const short8*)(Q1);
    qf[1][1] = *(const short8*)(Q1 + 512);

    short8 onesB = (short8){0,0,0,0,0,0,0,0};
    if (m == 0) {
        #pragma unroll
        for (int jj = 0; jj < 8; ++jj) onesB[jj] = (short)0x3F80;
    }

    f32x4 acc[2][5];
    #pragma unroll
    for (int rt = 0; rt < 2; ++rt)
        #pragma unroll
        for (int t = 0; t < 5; ++t) acc[rt][t] = (f32x4){0.f, 0.f, 0.f, 0.f};
    float mrun[2][4];
    #pragma unroll
    for (int rt = 0; rt < 2; ++rt)
        #pragma unroll
        for (int r = 0; r < 4; ++r) mrun[rt][r] = -INFINITY;

    const unsigned short* Kbase = Kf + (size_t)(b * 256) * 1024 + lane * 8;
    const unsigned short* Vbase = Vf + (size_t)(b * 128) * 2048 + lane * 8;

    // preload first step (s = w)
    short8 kf[4], vf[4];
    if (w < ns1) {
        #pragma unroll
        for (int t = 0; t < 4; ++t) {
            kf[t] = *(const short8*)(Kbase + (size_t)w * 2048 + t * 512);
            vf[t] = *(const short8*)(Vbase + (size_t)w * 2048 + t * 512);
        }
    }

    for (int s = w; s < ns1; s += 8) {
        int kv0 = s * 32;
        int sn = s + 8;
        // prefetch next step into dedicated regs (L2 latency hides under compute)
        short8 kn[4], vn[4];
        if (sn < ns1) {
            #pragma unroll
            for (int t = 0; t < 4; ++t) {
                kn[t] = *(const short8*)(Kbase + (size_t)sn * 2048 + t * 512);
                vn[t] = *(const short8*)(Vbase + (size_t)sn * 2048 + t * 512);
            }
        }

        #pragma unroll
        for (int rt = 0; rt < 2; ++rt) {
            if (rt == 0 && s >= ns0) continue;
            int qbase = (rt == 0) ? base0 : base1;
            bool lastd = (s == ((rt == 0) ? ns0 : ns1) - 1);

            f32x4 sc[2];
            sc[0] = (f32x4){0.f, 0.f, 0.f, 0.f};
            sc[1] = (f32x4){0.f, 0.f, 0.f, 0.f};
            sc[0] = __builtin_amdgcn_mfma_f32_16x16x32_bf16(qf[rt][0], kf[0], sc[0], 0, 0, 0);
            sc[0] = __builtin_amdgcn_mfma_f32_16x16x32_bf16(qf[rt][1], kf[1], sc[0], 0, 0, 0);
            sc[1] = __builtin_amdgcn_mfma_f32_16x16x32_bf16(qf[rt][0], kf[2], sc[1], 0, 0, 0);
            sc[1] = __builtin_amdgcn_mfma_f32_16x16x32_bf16(qf[rt][1], kf[3], sc[1], 0, 0, 0);

            if (lastd) {
                #pragma unroll
                for (int tt = 0; tt < 2; ++tt)
                    #pragma unroll
                    for (int r = 0; r < 4; ++r)
                        if (kv0 + tt * 16 + m > qbase + g * 4 + r) sc[tt][r] = -INFINITY;
            }

            bool need = false;
            #pragma unroll
            for (int r = 0; r < 4; ++r) {
                float th = mrun[rt][r] + 8.0f;
                need = need | (sc[0][r] > th) | (sc[1][r] > th);
            }
            if (__any(need)) {
                float rmax[4];
                #pragma unroll
                for (int r = 0; r < 4; ++r) rmax[r] = fmaxf(sc[0][r], sc[1][r]);
                #pragma unroll
                for (int msk = 1; msk <= 8; msk <<= 1)
                    #pragma unroll
                    for (int r = 0; r < 4; ++r)
                        rmax[r] = fmaxf(rmax[r], __shfl_xor(rmax[r], msk));
                #pragma unroll
                for (int r = 0; r < 4; ++r) {
                    float mnew = fmaxf(mrun[rt][r], rmax[r]);
                    float alpha = __builtin_amdgcn_exp2f(mrun[rt][r] - mnew);
                    mrun[rt][r] = mnew;
                    #pragma unroll
                    for (int t = 0; t < 5; ++t) acc[rt][t][r] *= alpha;
                }
            }

            #pragma unroll
            for (int tt = 0; tt < 2; ++tt)
                #pragma unroll
                for (int r = 0; r < 4; ++r)
                    P_lds[w][rt * 16 + g * 4 + r][tt * 16 + m] =
                        f2bf(__builtin_amdgcn_exp2f(sc[tt][r] - mrun[rt][r]));
            short8 pa = *(const short8*)&P_lds[w][rt * 16 + m][g * 8];

            #pragma unroll
            for (int t = 0; t < 4; ++t)
                acc[rt][t] = __builtin_amdgcn_mfma_f32_16x16x32_bf16(pa, vf[t], acc[rt][t], 0, 0, 0);
            acc[rt][4] = __builtin_amdgcn_mfma_f32_16x16x32_bf16(pa, onesB, acc[rt][4], 0, 0, 0);
        }

        if (sn < ns1) {
            #pragma unroll
            for (int t = 0; t < 4; ++t) { kf[t] = kn[t]; vf[t] = vn[t]; }
        }
    }

    #pragma unroll
    for (int rt = 0; rt < 2; ++rt) {
        int qbase = (rt == 0) ? base0 : base1;
        if (m == 0) {
            #pragma unroll
            for (int r = 0; r < 4; ++r) {
                pm[w][g * 4 + r] = mrun[rt][r];
                pl[w][g * 4 + r] = acc[rt][4][r];
            }
        }
        #pragma unroll
        for (int t = 0; t < 4; ++t)
            #pragma unroll
            for (int r = 0; r < 4; ++r)
                pacc[w][g * 4 + r][t * 16 + m] = f2bf(acc[rt][t][r]);
        __syncthreads();

        if (tid < 256) {
            int row = tid >> 4;
            int c4 = (tid & 15) * 4;
            float mmax = pm[0][row];
            #pragma unroll
            for (int w2 = 1; w2 < 8; ++w2) mmax = fmaxf(mmax, pm[w2][row]);
            float lt = 0.f;
            float o0 = 0.f, o1 = 0.f, o2 = 0.f, o3 = 0.f;
            #pragma unroll
            for (int w2 = 0; w2 < 8; ++w2) {
                float sc2 = __builtin_amdgcn_exp2f(pm[w2][row] - mmax);
                lt += pl[w2][row] * sc2;
                short4v pa4 = *(const short4v*)&pacc[w2][row][c4];
                o0 += bf2f((unsigned short)pa4[0]) * sc2;
                o1 += bf2f((unsigned short)pa4[1]) * sc2;
                o2 += bf2f((unsigned short)pa4[2]) * sc2;
                o3 += bf2f((unsigned short)pa4[3]) * sc2;
            }
            float invl = 1.0f / lt;
            float4 res = make_float4(o0 * invl, o1 * invl, o2 * invl, o3 * invl);
            *(float4*)&out[(size_t)(b * SEQ + qbase + row) * DOUT + c4] = res;
        }
        __syncthreads();
    }
}

// ---------------------------------------------------------------------------
extern "C" void kernel_launch(void* const* d_in, const int* in_sizes, int n_in,
                              void* d_out, int out_size, void* d_ws, size_t ws_size,
                              hipStream_t stream) {
    const float* x  = (const float*)d_in[0];
    const float* wq = (const float*)d_in[1];
    const float* bq = (const float*)d_in[2];
    const float* wk = (const float*)d_in[3];
    const float* bk = (const float*)d_in[4];
    const float* wv = (const float*)d_in[5];
    const float* bv = (const float*)d_in[6];
    float* out = (float*)d_out;

    char* ws = (char*)d_ws;
    unsigned short* wF = (unsigned short*)ws;                       // 294912 B
    unsigned short* Qf = (unsigned short*)(ws + 294912);            // 2 MB
    unsigned short* Kf = (unsigned short*)(ws + 294912 + 2097152);  // 2 MB
    unsigned short* Vf = (unsigned short*)(ws + 294912 + 4194304);  // 2 MB

    wprep_kernel<<<36, 256, 0, stream>>>(wq, wk, wv, wF);
    proj_kernel<<<512, 256, 0, stream>>>(x, bq, bk, bv, wF, Qf, Kf, Vf);
    attn_kernel<<<512, 512, 0, stream>>>(Qf, Kf, Vf, out);
}

// Round 16
// 51.653 us; speedup vs baseline: 1.1007x; 1.1007x over previous
//
#include <hip/hip_runtime.h>
#include <hip/hip_bf16.h>

#define BATCH 4
#define SEQ   4096
#define DIN   768
#define DOUT  64

typedef __attribute__((ext_vector_type(4))) float f32x4;
typedef __attribute__((ext_vector_type(8))) short short8;
typedef __attribute__((ext_vector_type(4))) short short4v;

#define QSCALE 0.18033688011112043f  /* 0.125 * log2(e) */

static __device__ __forceinline__ unsigned short f2bf(float f) {
    union { float f; unsigned u; } un; un.f = f;
    unsigned r = un.u + 0x7FFF + ((un.u >> 16) & 1);
    return (unsigned short)(r >> 16);
}
static __device__ __forceinline__ float bf2f(unsigned short h) {
    union { unsigned u; float f; } un; un.u = ((unsigned)h) << 16;
    return un.f;
}

// ---------------------------------------------------------------------------
// Kernel 0 (v2, unchanged): weights -> B-fragment order.
// ---------------------------------------------------------------------------
__global__ void wprep_kernel(const float* __restrict__ wq,
                             const float* __restrict__ wk,
                             const float* __restrict__ wv,
                             unsigned short* __restrict__ wF) {
    __shared__ float lds[64][65];
    int o = blockIdx.x / 12, kt = blockIdx.x % 12;
    const float* w = (o == 0) ? wq : (o == 1) ? wk : wv;
    int tid = threadIdx.x;
    int k0 = kt * 64;
    #pragma unroll
    for (int i = 0; i < 16; ++i) {
        int flat = tid + i * 256;
        int kl = flat >> 6, n = flat & 63;
        lds[kl][n] = w[(k0 + kl) * 64 + n];
    }
    __syncthreads();
    int lane = tid & 63;
    int m = lane & 15, g = lane >> 4;
    #pragma unroll
    for (int i = 0; i < 2; ++i) {
        int f = i * 4 + (tid >> 6);
        int t = f >> 1, kcl = f & 1;
        int kc = kt * 2 + kcl;
        int nc = o * 4 + t;
        short8 v;
        #pragma unroll
        for (int j = 0; j < 8; ++j)
            v[j] = (short)f2bf(lds[kcl * 32 + g * 8 + j][t * 16 + m]);
        *(short8*)&wF[(size_t)(nc * 24 + kc) * 512 + lane * 8] = v;
    }
}

// ---------------------------------------------------------------------------
// Kernel 1 (v8, unchanged): QKV projection, fragment-order I/O, 32 rows/blk.
// ---------------------------------------------------------------------------
__global__ void __launch_bounds__(256) proj_kernel(
        const float* __restrict__ x,
        const float* __restrict__ bq,
        const float* __restrict__ bk,
        const float* __restrict__ bv,
        const unsigned short* __restrict__ wF,
        unsigned short* __restrict__ Qf,
        unsigned short* __restrict__ Kf,
        unsigned short* __restrict__ Vf) {
    __shared__ __align__(16) unsigned short xs[32][776];   // 48.5 KB
    __shared__ unsigned short tr[4][16][24];               // 3 KB

    int tid = threadIdx.x;
    int w = tid >> 6;
    int lane = tid & 63;
    int m = lane & 15, g = lane >> 4;
    int r0 = blockIdx.x * 32;

    {
        const float* xbase = x + (size_t)r0 * DIN;
        #pragma unroll
        for (int i = 0; i < 24; ++i) {
            int flat4 = tid + i * 256;
            int row = flat4 / 192;
            int c4 = flat4 - row * 192;
            float4 v = *(const float4*)(xbase + (size_t)row * DIN + c4 * 4);
            short4v sv;
            sv[0] = (short)f2bf(v.x); sv[1] = (short)f2bf(v.y);
            sv[2] = (short)f2bf(v.z); sv[3] = (short)f2bf(v.w);
            *(short4v*)&xs[row][c4 * 4] = sv;
        }
    }
    __syncthreads();

    f32x4 acc[2][3];
    #pragma unroll
    for (int st = 0; st < 2; ++st)
        #pragma unroll
        for (int t = 0; t < 3; ++t) acc[st][t] = (f32x4){0.f, 0.f, 0.f, 0.f};

    for (int kc = 0; kc < 24; ++kc) {
        short8 af0 = *(const short8*)&xs[m][kc * 32 + g * 8];
        short8 af1 = *(const short8*)&xs[16 + m][kc * 32 + g * 8];
        #pragma unroll
        for (int tt = 0; tt < 3; ++tt) {
            int nc = w * 3 + tt;
            short8 bfrg = *(const short8*)(wF + (size_t)(nc * 24 + kc) * 512 + lane * 8);
            acc[0][tt] = __builtin_amdgcn_mfma_f32_16x16x32_bf16(af0, bfrg, acc[0][tt], 0, 0, 0);
            acc[1][tt] = __builtin_amdgcn_mfma_f32_16x16x32_bf16(af1, bfrg, acc[1][tt], 0, 0, 0);
        }
    }

    int b2 = r0 >> 12;
    int s = (r0 & 4095) >> 5;
    #pragma unroll
    for (int st = 0; st < 2; ++st) {
        #pragma unroll
        for (int tt = 0; tt < 3; ++tt) {
            int nc = w * 3 + tt;
            int o = nc >> 2;
            int t = nc & 3;
            const float* bias_p = (o == 0) ? bq : (o == 1) ? bk : bv;
            float bias = bias_p[t * 16 + m];
            #pragma unroll
            for (int r = 0; r < 4; ++r) {
                float val = acc[st][tt][r] + bias;
                if (o == 0) val *= QSCALE;
                tr[w][g * 4 + r][m] = f2bf(val);
            }
            if (o < 2) {
                if (g < 2) {
                    short8 v8;
                    #pragma unroll
                    for (int j = 0; j < 8; ++j) v8[j] = (short)tr[w][m][g * 8 + j];
                    unsigned short* dst = (o == 0) ? Qf : Kf;
                    int c = t >> 1;
                    *(short8*)&dst[(size_t)((blockIdx.x * 2 + st) * 2 + c) * 512
                                   + (((t & 1) * 2 + g) * 16 + m) * 8] = v8;
                }
            } else {
                if (g < 2) {
                    short8 v8;
                    #pragma unroll
                    for (int j = 0; j < 8; ++j) v8[j] = (short)tr[w][g * 8 + j][m];
                    *(short8*)&Vf[((size_t)(b2 * 128 + s) * 4 + t) * 512
                                  + ((st * 2 + g) * 16 + m) * 8] = v8;
                }
            }
        }
    }
}

// ---------------------------------------------------------------------------
// Kernel 2 (v10): complementary pairing + IN-PLACE ROTATED K/V PIPELINE
// at __launch_bounds__(512, 2).
// Round-15 evidence: explicit pipeline = 1.76x per-wave speedup but its +32
// prefetch VGPRs forced (512,1) and lost 2x TLP. Here the next step's K
// loads into kf RIGHT AFTER rt1's QK (kf's last read); next V loads into vf
// AFTER rt1's PV (vf's last read). Zero extra registers -> ~120 VGPR fits
// the 128 budget -> keeps 4 waves/SIMD AND hides L2 latency.
// ---------------------------------------------------------------------------
__global__ void __launch_bounds__(512, 2) attn_kernel(
        const unsigned short* __restrict__ Qf,
        const unsigned short* __restrict__ Kf,
        const unsigned short* __restrict__ Vf,
        float* __restrict__ out) {
    __shared__ __align__(16) unsigned short P_lds[8][32][36];
    __shared__ __align__(16) unsigned short pacc[8][16][68];
    __shared__ float pm[8][16];
    __shared__ float pl[8][16];

    int j = blockIdx.x;
    int b = j & 3;
    int qt = j >> 2;                       // 0..127
    int base0 = qt * 16;                   // shallow tile rows
    int base1 = (255 - qt) * 16;           // deep tile rows
    int ns0 = (qt + 2) >> 1;
    int ns1 = (257 - qt) >> 1;
    int tid = threadIdx.x;
    int w = tid >> 6;
    int lane = tid & 63;
    int m = lane & 15, g = lane >> 4;

    const unsigned short* Q0 = Qf + (size_t)(b * 256 + qt) * 1024 + lane * 8;
    const unsigned short* Q1 = Qf + (size_t)(b * 256 + 255 - qt) * 1024 + lane * 8;
    short8 qf00 = *(const short8*)(Q0);
    short8 qf01 = *(const short8*)(Q0 + 512);
    short8 qf10 = *(const short8*)(Q1);
    short8 qf11 = *(const short8*)(Q1 + 512);

    short8 onesB = (short8){0,0,0,0,0,0,0,0};
    if (m == 0) {
        #pragma unroll
        for (int jj = 0; jj < 8; ++jj) onesB[jj] = (short)0x3F80;
    }

    f32x4 acc[2][5];
    #pragma unroll
    for (int rt = 0; rt < 2; ++rt)
        #pragma unroll
        for (int t = 0; t < 5; ++t) acc[rt][t] = (f32x4){0.f, 0.f, 0.f, 0.f};
    float mrun[2][4];
    #pragma unroll
    for (int rt = 0; rt < 2; ++rt)
        #pragma unroll
        for (int r = 0; r < 4; ++r) mrun[rt][r] = -INFINITY;

    const unsigned short* Kbase = Kf + (size_t)(b * 256) * 1024 + lane * 8;
    const unsigned short* Vbase = Vf + (size_t)(b * 128) * 2048 + lane * 8;

    // preload first step (s = w)
    short8 kf[4], vf[4];
    if (w < ns1) {
        #pragma unroll
        for (int t = 0; t < 4; ++t) {
            kf[t] = *(const short8*)(Kbase + (size_t)w * 2048 + t * 512);
            vf[t] = *(const short8*)(Vbase + (size_t)w * 2048 + t * 512);
        }
    }

    for (int s = w; s < ns1; s += 8) {
        int kv0 = s * 32;
        int sn = s + 8;
        bool have = (sn < ns1);
        bool do0 = (s < ns0);

        // ================= rt0 (shallow tile) =================
        if (do0) {
            f32x4 sc0 = (f32x4){0.f, 0.f, 0.f, 0.f};
            f32x4 sc1 = (f32x4){0.f, 0.f, 0.f, 0.f};
            sc0 = __builtin_amdgcn_mfma_f32_16x16x32_bf16(qf00, kf[0], sc0, 0, 0, 0);
            sc0 = __builtin_amdgcn_mfma_f32_16x16x32_bf16(qf01, kf[1], sc0, 0, 0, 0);
            sc1 = __builtin_amdgcn_mfma_f32_16x16x32_bf16(qf00, kf[2], sc1, 0, 0, 0);
            sc1 = __builtin_amdgcn_mfma_f32_16x16x32_bf16(qf01, kf[3], sc1, 0, 0, 0);
            if (s == ns0 - 1) {
                #pragma unroll
                for (int r = 0; r < 4; ++r) {
                    if (kv0 + m > base0 + g * 4 + r) sc0[r] = -INFINITY;
                    if (kv0 + 16 + m > base0 + g * 4 + r) sc1[r] = -INFINITY;
                }
            }
            bool need = false;
            #pragma unroll
            for (int r = 0; r < 4; ++r) {
                float th = mrun[0][r] + 8.0f;
                need = need | (sc0[r] > th) | (sc1[r] > th);
            }
            if (__any(need)) {
                float rmax[4];
                #pragma unroll
                for (int r = 0; r < 4; ++r) rmax[r] = fmaxf(sc0[r], sc1[r]);
                #pragma unroll
                for (int msk = 1; msk <= 8; msk <<= 1)
                    #pragma unroll
                    for (int r = 0; r < 4; ++r)
                        rmax[r] = fmaxf(rmax[r], __shfl_xor(rmax[r], msk));
                #pragma unroll
                for (int r = 0; r < 4; ++r) {
                    float mnew = fmaxf(mrun[0][r], rmax[r]);
                    float alpha = __builtin_amdgcn_exp2f(mrun[0][r] - mnew);
                    mrun[0][r] = mnew;
                    #pragma unroll
                    for (int t = 0; t < 5; ++t) acc[0][t][r] *= alpha;
                }
            }
            #pragma unroll
            for (int r = 0; r < 4; ++r) {
                P_lds[w][g * 4 + r][m]      = f2bf(__builtin_amdgcn_exp2f(sc0[r] - mrun[0][r]));
                P_lds[w][g * 4 + r][16 + m] = f2bf(__builtin_amdgcn_exp2f(sc1[r] - mrun[0][r]));
            }
            short8 pa = *(const short8*)&P_lds[w][m][g * 8];
            #pragma unroll
            for (int t = 0; t < 4; ++t)
                acc[0][t] = __builtin_amdgcn_mfma_f32_16x16x32_bf16(pa, vf[t], acc[0][t], 0, 0, 0);
            acc[0][4] = __builtin_amdgcn_mfma_f32_16x16x32_bf16(pa, onesB, acc[0][4], 0, 0, 0);
        }

        // ================= rt1 (deep tile) =================
        {
            f32x4 sc0 = (f32x4){0.f, 0.f, 0.f, 0.f};
            f32x4 sc1 = (f32x4){0.f, 0.f, 0.f, 0.f};
            sc0 = __builtin_amdgcn_mfma_f32_16x16x32_bf16(qf10, kf[0], sc0, 0, 0, 0);
            sc0 = __builtin_amdgcn_mfma_f32_16x16x32_bf16(qf11, kf[1], sc0, 0, 0, 0);
            sc1 = __builtin_amdgcn_mfma_f32_16x16x32_bf16(qf10, kf[2], sc1, 0, 0, 0);
            sc1 = __builtin_amdgcn_mfma_f32_16x16x32_bf16(qf11, kf[3], sc1, 0, 0, 0);

            // kf's last read was above -> reload IN PLACE for step s+8.
            // Latency hides under the softmax/P/PV below + next-iter slack.
            if (have) {
                #pragma unroll
                for (int t = 0; t < 4; ++t)
                    kf[t] = *(const short8*)(Kbase + (size_t)sn * 2048 + t * 512);
            }

            if (s == ns1 - 1) {
                #pragma unroll
                for (int r = 0; r < 4; ++r) {
                    if (kv0 + m > base1 + g * 4 + r) sc0[r] = -INFINITY;
                    if (kv0 + 16 + m > base1 + g * 4 + r) sc1[r] = -INFINITY;
                }
            }
            bool need = false;
            #pragma unroll
            for (int r = 0; r < 4; ++r) {
                float th = mrun[1][r] + 8.0f;
                need = need | (sc0[r] > th) | (sc1[r] > th);
            }
            if (__any(need)) {
                float rmax[4];
                #pragma unroll
                for (int r = 0; r < 4; ++r) rmax[r] = fmaxf(sc0[r], sc1[r]);
                #pragma unroll
                for (int msk = 1; msk <= 8; msk <<= 1)
                    #pragma unroll
                    for (int r = 0; r < 4; ++r)
                        rmax[r] = fmaxf(rmax[r], __shfl_xor(rmax[r], msk));
                #pragma unroll
                for (int r = 0; r < 4; ++r) {
                    float mnew = fmaxf(mrun[1][r], rmax[r]);
                    float alpha = __builtin_amdgcn_exp2f(mrun[1][r] - mnew);
                    mrun[1][r] = mnew;
                    #pragma unroll
                    for (int t = 0; t < 5; ++t) acc[1][t][r] *= alpha;
                }
            }
            #pragma unroll
            for (int r = 0; r < 4; ++r) {
                P_lds[w][16 + g * 4 + r][m]      = f2bf(__builtin_amdgcn_exp2f(sc0[r] - mrun[1][r]));
                P_lds[w][16 + g * 4 + r][16 + m] = f2bf(__builtin_amdgcn_exp2f(sc1[r] - mrun[1][r]));
            }
            short8 pa = *(const short8*)&P_lds[w][16 + m][g * 8];
            #pragma unroll
            for (int t = 0; t < 4; ++t)
                acc[1][t] = __builtin_amdgcn_mfma_f32_16x16x32_bf16(pa, vf[t], acc[1][t], 0, 0, 0);
            acc[1][4] = __builtin_amdgcn_mfma_f32_16x16x32_bf16(pa, onesB, acc[1][4], 0, 0, 0);

            // vf's last read was above -> reload IN PLACE for step s+8.
            if (have) {
                #pragma unroll
                for (int t = 0; t < 4; ++t)
                    vf[t] = *(const short8*)(Vbase + (size_t)sn * 2048 + t * 512);
            }
        }
    }

    #pragma unroll
    for (int rt = 0; rt < 2; ++rt) {
        int qbase = (rt == 0) ? base0 : base1;
        if (m == 0) {
            #pragma unroll
            for (int r = 0; r < 4; ++r) {
                pm[w][g * 4 + r] = mrun[rt][r];
                pl[w][g * 4 + r] = acc[rt][4][r];
            }
        }
        #pragma unroll
        for (int t = 0; t < 4; ++t)
            #pragma unroll
            for (int r = 0; r < 4; ++r)
                pacc[w][g * 4 + r][t * 16 + m] = f2bf(acc[rt][t][r]);
        __syncthreads();

        if (tid < 256) {
            int row = tid >> 4;
            int c4 = (tid & 15) * 4;
            float mmax = pm[0][row];
            #pragma unroll
            for (int w2 = 1; w2 < 8; ++w2) mmax = fmaxf(mmax, pm[w2][row]);
            float lt = 0.f;
            float o0 = 0.f, o1 = 0.f, o2 = 0.f, o3 = 0.f;
            #pragma unroll
            for (int w2 = 0; w2 < 8; ++w2) {
                float sc2 = __builtin_amdgcn_exp2f(pm[w2][row] - mmax);
                lt += pl[w2][row] * sc2;
                short4v pa4 = *(const short4v*)&pacc[w2][row][c4];
                o0 += bf2f((unsigned short)pa4[0]) * sc2;
                o1 += bf2f((unsigned short)pa4[1]) * sc2;
                o2 += bf2f((unsigned short)pa4[2]) * sc2;
                o3 += bf2f((unsigned short)pa4[3]) * sc2;
            }
            float invl = 1.0f / lt;
            float4 res = make_float4(o0 * invl, o1 * invl, o2 * invl, o3 * invl);
            *(float4*)&out[(size_t)(b * SEQ + qbase + row) * DOUT + c4] = res;
        }
        __syncthreads();
    }
}

// ---------------------------------------------------------------------------
extern "C" void kernel_launch(void* const* d_in, const int* in_sizes, int n_in,
                              void* d_out, int out_size, void* d_ws, size_t ws_size,
                              hipStream_t stream) {
    const float* x  = (const float*)d_in[0];
    const float* wq = (const float*)d_in[1];
    const float* bq = (const float*)d_in[2];
    const float* wk = (const float*)d_in[3];
    const float* bk = (const float*)d_in[4];
    const float* wv = (const float*)d_in[5];
    const float* bv = (const float*)d_in[6];
    float* out = (float*)d_out;

    char* ws = (char*)d_ws;
    unsigned short* wF = (unsigned short*)ws;                       // 294912 B
    unsigned short* Qf = (unsigned short*)(ws + 294912);            // 2 MB
    unsigned short* Kf = (unsigned short*)(ws + 294912 + 2097152);  // 2 MB
    unsigned short* Vf = (unsigned short*)(ws + 294912 + 4194304);  // 2 MB

    wprep_kernel<<<36, 256, 0, stream>>>(wq, wk, wv, wF);
    proj_kernel<<<512, 256, 0, stream>>>(x, bq, bk, bv, wF, Qf, Kf, Vf);
    attn_kernel<<<512, 512, 0, stream>>>(Qf, Kf, Vf, out);
}

// Round 17
// 49.467 us; speedup vs baseline: 1.1493x; 1.0442x over previous
//
#include <hip/hip_runtime.h>
#include <hip/hip_bf16.h>

#define BATCH 4
#define SEQ   4096
#define DIN   768
#define DOUT  64

typedef __attribute__((ext_vector_type(4))) float f32x4;
typedef __attribute__((ext_vector_type(8))) short short8;
typedef __attribute__((ext_vector_type(4))) short short4v;

#define QSCALE 0.18033688011112043f  /* 0.125 * log2(e) */

static __device__ __forceinline__ unsigned short f2bf(float f) {
    union { float f; unsigned u; } un; un.f = f;
    unsigned r = un.u + 0x7FFF + ((un.u >> 16) & 1);
    return (unsigned short)(r >> 16);
}
static __device__ __forceinline__ float bf2f(unsigned short h) {
    union { unsigned u; float f; } un; un.u = ((unsigned)h) << 16;
    return un.f;
}
static __device__ __forceinline__ unsigned packbf(float lo, float hi) {
    return ((unsigned)f2bf(hi) << 16) | (unsigned)f2bf(lo);
}

// ---------------------------------------------------------------------------
// Kernel 0 (v2, unchanged): weights -> B-fragment order.
// ---------------------------------------------------------------------------
__global__ void wprep_kernel(const float* __restrict__ wq,
                             const float* __restrict__ wk,
                             const float* __restrict__ wv,
                             unsigned short* __restrict__ wF) {
    __shared__ float lds[64][65];
    int o = blockIdx.x / 12, kt = blockIdx.x % 12;
    const float* w = (o == 0) ? wq : (o == 1) ? wk : wv;
    int tid = threadIdx.x;
    int k0 = kt * 64;
    #pragma unroll
    for (int i = 0; i < 16; ++i) {
        int flat = tid + i * 256;
        int kl = flat >> 6, n = flat & 63;
        lds[kl][n] = w[(k0 + kl) * 64 + n];
    }
    __syncthreads();
    int lane = tid & 63;
    int m = lane & 15, g = lane >> 4;
    #pragma unroll
    for (int i = 0; i < 2; ++i) {
        int f = i * 4 + (tid >> 6);
        int t = f >> 1, kcl = f & 1;
        int kc = kt * 2 + kcl;
        int nc = o * 4 + t;
        short8 v;
        #pragma unroll
        for (int j = 0; j < 8; ++j)
            v[j] = (short)f2bf(lds[kcl * 32 + g * 8 + j][t * 16 + m]);
        *(short8*)&wF[(size_t)(nc * 24 + kc) * 512 + lane * 8] = v;
    }
}

// ---------------------------------------------------------------------------
// Kernel 1 (v8, unchanged): QKV projection, fragment-order I/O, 32 rows/blk.
// ---------------------------------------------------------------------------
__global__ void __launch_bounds__(256) proj_kernel(
        const float* __restrict__ x,
        const float* __restrict__ bq,
        const float* __restrict__ bk,
        const float* __restrict__ bv,
        const unsigned short* __restrict__ wF,
        unsigned short* __restrict__ Qf,
        unsigned short* __restrict__ Kf,
        unsigned short* __restrict__ Vf) {
    __shared__ __align__(16) unsigned short xs[32][776];   // 48.5 KB
    __shared__ unsigned short tr[4][16][24];               // 3 KB

    int tid = threadIdx.x;
    int w = tid >> 6;
    int lane = tid & 63;
    int m = lane & 15, g = lane >> 4;
    int r0 = blockIdx.x * 32;

    {
        const float* xbase = x + (size_t)r0 * DIN;
        #pragma unroll
        for (int i = 0; i < 24; ++i) {
            int flat4 = tid + i * 256;
            int row = flat4 / 192;
            int c4 = flat4 - row * 192;
            float4 v = *(const float4*)(xbase + (size_t)row * DIN + c4 * 4);
            short4v sv;
            sv[0] = (short)f2bf(v.x); sv[1] = (short)f2bf(v.y);
            sv[2] = (short)f2bf(v.z); sv[3] = (short)f2bf(v.w);
            *(short4v*)&xs[row][c4 * 4] = sv;
        }
    }
    __syncthreads();

    f32x4 acc[2][3];
    #pragma unroll
    for (int st = 0; st < 2; ++st)
        #pragma unroll
        for (int t = 0; t < 3; ++t) acc[st][t] = (f32x4){0.f, 0.f, 0.f, 0.f};

    for (int kc = 0; kc < 24; ++kc) {
        short8 af0 = *(const short8*)&xs[m][kc * 32 + g * 8];
        short8 af1 = *(const short8*)&xs[16 + m][kc * 32 + g * 8];
        #pragma unroll
        for (int tt = 0; tt < 3; ++tt) {
            int nc = w * 3 + tt;
            short8 bfrg = *(const short8*)(wF + (size_t)(nc * 24 + kc) * 512 + lane * 8);
            acc[0][tt] = __builtin_amdgcn_mfma_f32_16x16x32_bf16(af0, bfrg, acc[0][tt], 0, 0, 0);
            acc[1][tt] = __builtin_amdgcn_mfma_f32_16x16x32_bf16(af1, bfrg, acc[1][tt], 0, 0, 0);
        }
    }

    int b2 = r0 >> 12;
    int s = (r0 & 4095) >> 5;
    #pragma unroll
    for (int st = 0; st < 2; ++st) {
        #pragma unroll
        for (int tt = 0; tt < 3; ++tt) {
            int nc = w * 3 + tt;
            int o = nc >> 2;
            int t = nc & 3;
            const float* bias_p = (o == 0) ? bq : (o == 1) ? bk : bv;
            float bias = bias_p[t * 16 + m];
            #pragma unroll
            for (int r = 0; r < 4; ++r) {
                float val = acc[st][tt][r] + bias;
                if (o == 0) val *= QSCALE;
                tr[w][g * 4 + r][m] = f2bf(val);
            }
            if (o < 2) {
                if (g < 2) {
                    short8 v8;
                    #pragma unroll
                    for (int j = 0; j < 8; ++j) v8[j] = (short)tr[w][m][g * 8 + j];
                    unsigned short* dst = (o == 0) ? Qf : Kf;
                    int c = t >> 1;
                    *(short8*)&dst[(size_t)((blockIdx.x * 2 + st) * 2 + c) * 512
                                   + (((t & 1) * 2 + g) * 16 + m) * 8] = v8;
                }
            } else {
                if (g < 2) {
                    short8 v8;
                    #pragma unroll
                    for (int j = 0; j < 8; ++j) v8[j] = (short)tr[w][g * 8 + j][m];
                    *(short8*)&Vf[((size_t)(b2 * 128 + s) * 4 + t) * 512
                                  + ((st * 2 + g) * 16 + m) * 8] = v8;
                }
            }
        }
    }
}

// ---------------------------------------------------------------------------
// Kernel 2 (v11): SWAPPED-QK IN-REGISTER SOFTMAX (T12-style).
// Compute S^T = mfma(A=K, B=Q) -> lane (m,g) holds S[kv=tt*16+g*4+r][q=m]:
// softmax stats (mrun,lsum) become ONE SCALAR per lane; P never touches LDS
// (8-shfl in-register transpose builds the PV B-fragment); PV computes
// O^T = mfma(A=V, B=P) whose layout matches the stats. Kf/Qf/Vf buffers are
// bit-identical as A/B frags under the swap -> proj/wprep unchanged.
// Drops: P_lds roundtrip (2x ~200cy/iter), ones-MFMAs (2/step), 14 shuffles
// on the rescale path. Keeps: pairing, in-place K/V rotation, (512,2).
// ---------------------------------------------------------------------------
__global__ void __launch_bounds__(512, 2) attn_kernel(
        const unsigned short* __restrict__ Qf,
        const unsigned short* __restrict__ Kf,
        const unsigned short* __restrict__ Vf,
        float* __restrict__ out) {
    __shared__ __align__(16) unsigned short pacc[8][16][68];
    __shared__ float pm[8][16];
    __shared__ float pl[8][16];

    int j = blockIdx.x;
    int b = j & 3;
    int qt = j >> 2;                       // 0..127
    int base0 = qt * 16;
    int base1 = (255 - qt) * 16;
    int ns0 = (qt + 2) >> 1;
    int ns1 = (257 - qt) >> 1;
    int tid = threadIdx.x;
    int w = tid >> 6;
    int lane = tid & 63;
    int m = lane & 15, g = lane >> 4;

    const unsigned short* Q0 = Qf + (size_t)(b * 256 + qt) * 1024 + lane * 8;
    const unsigned short* Q1 = Qf + (size_t)(b * 256 + 255 - qt) * 1024 + lane * 8;
    short8 qf00 = *(const short8*)(Q0);
    short8 qf01 = *(const short8*)(Q0 + 512);
    short8 qf10 = *(const short8*)(Q1);
    short8 qf11 = *(const short8*)(Q1 + 512);

    f32x4 acc[2][4];
    #pragma unroll
    for (int rt = 0; rt < 2; ++rt)
        #pragma unroll
        for (int t = 0; t < 4; ++t) acc[rt][t] = (f32x4){0.f, 0.f, 0.f, 0.f};
    float mrun0 = -INFINITY, mrun1 = -INFINITY;
    float lsum0 = 0.f, lsum1 = 0.f;

    const unsigned short* Kbase = Kf + (size_t)(b * 256) * 1024 + lane * 8;
    const unsigned short* Vbase = Vf + (size_t)(b * 128) * 2048 + lane * 8;

    // shuffle-transpose source lanes (constant per lane)
    int srcA = m + 16 * ((g & 1) * 2);
    int srcB = srcA + 16;
    bool hi = (g >= 2);

    short8 kf[4], vf[4];
    if (w < ns1) {
        #pragma unroll
        for (int t = 0; t < 4; ++t) {
            kf[t] = *(const short8*)(Kbase + (size_t)w * 2048 + t * 512);
            vf[t] = *(const short8*)(Vbase + (size_t)w * 2048 + t * 512);
        }
    }

    for (int s = w; s < ns1; s += 8) {
        int kv0 = s * 32;
        int sn = s + 8;
        bool have = (sn < ns1);
        bool do0 = (s < ns0);

        // ================= rt0 (shallow tile) =================
        if (do0) {
            f32x4 st0 = (f32x4){0.f, 0.f, 0.f, 0.f};
            f32x4 st1 = (f32x4){0.f, 0.f, 0.f, 0.f};
            st0 = __builtin_amdgcn_mfma_f32_16x16x32_bf16(kf[0], qf00, st0, 0, 0, 0);
            st0 = __builtin_amdgcn_mfma_f32_16x16x32_bf16(kf[1], qf01, st0, 0, 0, 0);
            st1 = __builtin_amdgcn_mfma_f32_16x16x32_bf16(kf[2], qf00, st1, 0, 0, 0);
            st1 = __builtin_amdgcn_mfma_f32_16x16x32_bf16(kf[3], qf01, st1, 0, 0, 0);
            if (s == ns0 - 1) {
                int q = base0 + m;
                #pragma unroll
                for (int r = 0; r < 4; ++r) {
                    if (kv0 + g * 4 + r > q)      st0[r] = -INFINITY;
                    if (kv0 + 16 + g * 4 + r > q) st1[r] = -INFINITY;
                }
            }
            float th = mrun0 + 8.0f;
            bool need = (st0[0] > th) | (st0[1] > th) | (st0[2] > th) | (st0[3] > th)
                      | (st1[0] > th) | (st1[1] > th) | (st1[2] > th) | (st1[3] > th);
            if (__any(need)) {
                float rmax = fmaxf(fmaxf(fmaxf(st0[0], st0[1]), fmaxf(st0[2], st0[3])),
                                   fmaxf(fmaxf(st1[0], st1[1]), fmaxf(st1[2], st1[3])));
                rmax = fmaxf(rmax, __shfl_xor(rmax, 16));
                rmax = fmaxf(rmax, __shfl_xor(rmax, 32));
                float mnew = fmaxf(mrun0, rmax);
                float alpha = __builtin_amdgcn_exp2f(mrun0 - mnew);
                mrun0 = mnew;
                lsum0 *= alpha;
                #pragma unroll
                for (int t = 0; t < 4; ++t)
                    #pragma unroll
                    for (int r = 0; r < 4; ++r) acc[0][t][r] *= alpha;
            }
            float p00 = __builtin_amdgcn_exp2f(st0[0] - mrun0);
            float p01 = __builtin_amdgcn_exp2f(st0[1] - mrun0);
            float p02 = __builtin_amdgcn_exp2f(st0[2] - mrun0);
            float p03 = __builtin_amdgcn_exp2f(st0[3] - mrun0);
            float p10 = __builtin_amdgcn_exp2f(st1[0] - mrun0);
            float p11 = __builtin_amdgcn_exp2f(st1[1] - mrun0);
            float p12 = __builtin_amdgcn_exp2f(st1[2] - mrun0);
            float p13 = __builtin_amdgcn_exp2f(st1[3] - mrun0);
            float ssum = ((p00 + p01) + (p02 + p03)) + ((p10 + p11) + (p12 + p13));
            ssum += __shfl_xor(ssum, 16);
            ssum += __shfl_xor(ssum, 32);
            lsum0 += ssum;
            unsigned d0 = packbf(p00, p01), d1 = packbf(p02, p03);
            unsigned d2 = packbf(p10, p11), d3 = packbf(p12, p13);
            unsigned a0 = __shfl(d0, srcA), a1 = __shfl(d1, srcA);
            unsigned a2 = __shfl(d2, srcA), a3 = __shfl(d3, srcA);
            unsigned b0 = __shfl(d0, srcB), b1 = __shfl(d1, srcB);
            unsigned b2 = __shfl(d2, srcB), b3 = __shfl(d3, srcB);
            union { unsigned u[4]; short8 s8; } pb;
            pb.u[0] = hi ? a2 : a0; pb.u[1] = hi ? a3 : a1;
            pb.u[2] = hi ? b2 : b0; pb.u[3] = hi ? b3 : b1;
            #pragma unroll
            for (int t = 0; t < 4; ++t)
                acc[0][t] = __builtin_amdgcn_mfma_f32_16x16x32_bf16(vf[t], pb.s8, acc[0][t], 0, 0, 0);
        }

        // ================= rt1 (deep tile) =================
        {
            f32x4 st0 = (f32x4){0.f, 0.f, 0.f, 0.f};
            f32x4 st1 = (f32x4){0.f, 0.f, 0.f, 0.f};
            st0 = __builtin_amdgcn_mfma_f32_16x16x32_bf16(kf[0], qf10, st0, 0, 0, 0);
            st0 = __builtin_amdgcn_mfma_f32_16x16x32_bf16(kf[1], qf11, st0, 0, 0, 0);
            st1 = __builtin_amdgcn_mfma_f32_16x16x32_bf16(kf[2], qf10, st1, 0, 0, 0);
            st1 = __builtin_amdgcn_mfma_f32_16x16x32_bf16(kf[3], qf11, st1, 0, 0, 0);

            // kf last read above -> in-place reload for s+8
            if (have) {
                #pragma unroll
                for (int t = 0; t < 4; ++t)
                    kf[t] = *(const short8*)(Kbase + (size_t)sn * 2048 + t * 512);
            }

            if (s == ns1 - 1) {
                int q = base1 + m;
                #pragma unroll
                for (int r = 0; r < 4; ++r) {
                    if (kv0 + g * 4 + r > q)      st0[r] = -INFINITY;
                    if (kv0 + 16 + g * 4 + r > q) st1[r] = -INFINITY;
                }
            }
            float th = mrun1 + 8.0f;
            bool need = (st0[0] > th) | (st0[1] > th) | (st0[2] > th) | (st0[3] > th)
                      | (st1[0] > th) | (st1[1] > th) | (st1[2] > th) | (st1[3] > th);
            if (__any(need)) {
                float rmax = fmaxf(fmaxf(fmaxf(st0[0], st0[1]), fmaxf(st0[2], st0[3])),
                                   fmaxf(fmaxf(st1[0], st1[1]), fmaxf(st1[2], st1[3])));
                rmax = fmaxf(rmax, __shfl_xor(rmax, 16));
                rmax = fmaxf(rmax, __shfl_xor(rmax, 32));
                float mnew = fmaxf(mrun1, rmax);
                float alpha = __builtin_amdgcn_exp2f(mrun1 - mnew);
                mrun1 = mnew;
                lsum1 *= alpha;
                #pragma unroll
                for (int t = 0; t < 4; ++t)
                    #pragma unroll
                    for (int r = 0; r < 4; ++r) acc[1][t][r] *= alpha;
            }
            float p00 = __builtin_amdgcn_exp2f(st0[0] - mrun1);
            float p01 = __builtin_amdgcn_exp2f(st0[1] - mrun1);
            float p02 = __builtin_amdgcn_exp2f(st0[2] - mrun1);
            float p03 = __builtin_amdgcn_exp2f(st0[3] - mrun1);
            float p10 = __builtin_amdgcn_exp2f(st1[0] - mrun1);
            float p11 = __builtin_amdgcn_exp2f(st1[1] - mrun1);
            float p12 = __builtin_amdgcn_exp2f(st1[2] - mrun1);
            float p13 = __builtin_amdgcn_exp2f(st1[3] - mrun1);
            float ssum = ((p00 + p01) + (p02 + p03)) + ((p10 + p11) + (p12 + p13));
            ssum += __shfl_xor(ssum, 16);
            ssum += __shfl_xor(ssum, 32);
            lsum1 += ssum;
            unsigned d0 = packbf(p00, p01), d1 = packbf(p02, p03);
            unsigned d2 = packbf(p10, p11), d3 = packbf(p12, p13);
            unsigned a0 = __shfl(d0, srcA), a1 = __shfl(d1, srcA);
            unsigned a2 = __shfl(d2, srcA), a3 = __shfl(d3, srcA);
            unsigned b0 = __shfl(d0, srcB), b1 = __shfl(d1, srcB);
            unsigned b2 = __shfl(d2, srcB), b3 = __shfl(d3, srcB);
            union { unsigned u[4]; short8 s8; } pb;
            pb.u[0] = hi ? a2 : a0; pb.u[1] = hi ? a3 : a1;
            pb.u[2] = hi ? b2 : b0; pb.u[3] = hi ? b3 : b1;
            #pragma unroll
            for (int t = 0; t < 4; ++t)
                acc[1][t] = __builtin_amdgcn_mfma_f32_16x16x32_bf16(vf[t], pb.s8, acc[1][t], 0, 0, 0);

            // vf last read above -> in-place reload for s+8
            if (have) {
                #pragma unroll
                for (int t = 0; t < 4; ++t)
                    vf[t] = *(const short8*)(Vbase + (size_t)sn * 2048 + t * 512);
            }
        }
    }

    // ===== per-wave partials + combine (layout: acc = O^T[d][q=m]) =====
    #pragma unroll
    for (int rt = 0; rt < 2; ++rt) {
        int qbase = (rt == 0) ? base0 : base1;
        float mr = (rt == 0) ? mrun0 : mrun1;
        float ls = (rt == 0) ? lsum0 : lsum1;
        if (lane < 16) {          // g == 0: one writer per q
            pm[w][m] = mr;
            pl[w][m] = ls;
        }
        #pragma unroll
        for (int t = 0; t < 4; ++t)
            #pragma unroll
            for (int r = 0; r < 4; ++r)
                pacc[w][m][t * 16 + g * 4 + r] = f2bf(acc[rt][t][r]);
        __syncthreads();

        if (tid < 256) {
            int row = tid >> 4;
            int c4 = (tid & 15) * 4;
            float mmax = pm[0][row];
            #pragma unroll
            for (int w2 = 1; w2 < 8; ++w2) mmax = fmaxf(mmax, pm[w2][row]);
            float lt = 0.f;
            float o0 = 0.f, o1 = 0.f, o2 = 0.f, o3 = 0.f;
            #pragma unroll
            for (int w2 = 0; w2 < 8; ++w2) {
                float sc2 = __builtin_amdgcn_exp2f(pm[w2][row] - mmax);
                lt += pl[w2][row] * sc2;
                short4v pa4 = *(const short4v*)&pacc[w2][row][c4];
                o0 += bf2f((unsigned short)pa4[0]) * sc2;
                o1 += bf2f((unsigned short)pa4[1]) * sc2;
                o2 += bf2f((unsigned short)pa4[2]) * sc2;
                o3 += bf2f((unsigned short)pa4[3]) * sc2;
            }
            float invl = 1.0f / lt;
            float4 res = make_float4(o0 * invl, o1 * invl, o2 * invl, o3 * invl);
            *(float4*)&out[(size_t)(b * SEQ + qbase + row) * DOUT + c4] = res;
        }
        __syncthreads();
    }
}

// ---------------------------------------------------------------------------
extern "C" void kernel_launch(void* const* d_in, const int* in_sizes, int n_in,
                              void* d_out, int out_size, void* d_ws, size_t ws_size,
                              hipStream_t stream) {
    const float* x  = (const float*)d_in[0];
    const float* wq = (const float*)d_in[1];
    const float* bq = (const float*)d_in[2];
    const float* wk = (const float*)d_in[3];
    const float* bk = (const float*)d_in[4];
    const float* wv = (const float*)d_in[5];
    const float* bv = (const float*)d_in[6];
    float* out = (float*)d_out;

    char* ws = (char*)d_ws;
    unsigned short* wF = (unsigned short*)ws;                       // 294912 B
    unsigned short* Qf = (unsigned short*)(ws + 294912);            // 2 MB
    unsigned short* Kf = (unsigned short*)(ws + 294912 + 2097152);  // 2 MB
    unsigned short* Vf = (unsigned short*)(ws + 294912 + 4194304);  // 2 MB

    wprep_kernel<<<36, 256, 0, stream>>>(wq, wk, wv, wF);
    proj_kernel<<<512, 256, 0, stream>>>(x, bq, bk, bv, wF, Qf, Kf, Vf);
    attn_kernel<<<512, 512, 0, stream>>>(Qf, Kf, Vf, out);
}

// Round 18
// 49.127 us; speedup vs baseline: 1.1573x; 1.0069x over previous
//
#include <hip/hip_runtime.h>
#include <hip/hip_bf16.h>

#define BATCH 4
#define SEQ   4096
#define DIN   768
#define DOUT  64

typedef __attribute__((ext_vector_type(4))) float f32x4;
typedef __attribute__((ext_vector_type(8))) short short8;
typedef __attribute__((ext_vector_type(4))) short short4v;
typedef __attribute__((ext_vector_type(2))) unsigned uint2v;

#define QSCALE 0.18033688011112043f  /* 0.125 * log2(e) */

static __device__ __forceinline__ unsigned short f2bf(float f) {
    union { float f; unsigned u; } un; un.f = f;
    unsigned r = un.u + 0x7FFF + ((un.u >> 16) & 1);
    return (unsigned short)(r >> 16);
}
static __device__ __forceinline__ float bf2f(unsigned short h) {
    union { unsigned u; float f; } un; un.u = ((unsigned)h) << 16;
    return un.f;
}
static __device__ __forceinline__ unsigned packbf(float lo, float hi) {
    return ((unsigned)f2bf(hi) << 16) | (unsigned)f2bf(lo);
}

// ---------------------------------------------------------------------------
// Kernel 0 (v2, unchanged): weights -> B-fragment order.
// ---------------------------------------------------------------------------
__global__ void wprep_kernel(const float* __restrict__ wq,
                             const float* __restrict__ wk,
                             const float* __restrict__ wv,
                             unsigned short* __restrict__ wF) {
    __shared__ float lds[64][65];
    int o = blockIdx.x / 12, kt = blockIdx.x % 12;
    const float* w = (o == 0) ? wq : (o == 1) ? wk : wv;
    int tid = threadIdx.x;
    int k0 = kt * 64;
    #pragma unroll
    for (int i = 0; i < 16; ++i) {
        int flat = tid + i * 256;
        int kl = flat >> 6, n = flat & 63;
        lds[kl][n] = w[(k0 + kl) * 64 + n];
    }
    __syncthreads();
    int lane = tid & 63;
    int m = lane & 15, g = lane >> 4;
    #pragma unroll
    for (int i = 0; i < 2; ++i) {
        int f = i * 4 + (tid >> 6);
        int t = f >> 1, kcl = f & 1;
        int kc = kt * 2 + kcl;
        int nc = o * 4 + t;
        short8 v;
        #pragma unroll
        for (int j = 0; j < 8; ++j)
            v[j] = (short)f2bf(lds[kcl * 32 + g * 8 + j][t * 16 + m]);
        *(short8*)&wF[(size_t)(nc * 24 + kc) * 512 + lane * 8] = v;
    }
}

// ---------------------------------------------------------------------------
// Kernel 1 (v8, unchanged): QKV projection, fragment-order I/O, 32 rows/blk.
// ---------------------------------------------------------------------------
__global__ void __launch_bounds__(256) proj_kernel(
        const float* __restrict__ x,
        const float* __restrict__ bq,
        const float* __restrict__ bk,
        const float* __restrict__ bv,
        const unsigned short* __restrict__ wF,
        unsigned short* __restrict__ Qf,
        unsigned short* __restrict__ Kf,
        unsigned short* __restrict__ Vf) {
    __shared__ __align__(16) unsigned short xs[32][776];   // 48.5 KB
    __shared__ unsigned short tr[4][16][24];               // 3 KB

    int tid = threadIdx.x;
    int w = tid >> 6;
    int lane = tid & 63;
    int m = lane & 15, g = lane >> 4;
    int r0 = blockIdx.x * 32;

    {
        const float* xbase = x + (size_t)r0 * DIN;
        #pragma unroll
        for (int i = 0; i < 24; ++i) {
            int flat4 = tid + i * 256;
            int row = flat4 / 192;
            int c4 = flat4 - row * 192;
            float4 v = *(const float4*)(xbase + (size_t)row * DIN + c4 * 4);
            short4v sv;
            sv[0] = (short)f2bf(v.x); sv[1] = (short)f2bf(v.y);
            sv[2] = (short)f2bf(v.z); sv[3] = (short)f2bf(v.w);
            *(short4v*)&xs[row][c4 * 4] = sv;
        }
    }
    __syncthreads();

    f32x4 acc[2][3];
    #pragma unroll
    for (int st = 0; st < 2; ++st)
        #pragma unroll
        for (int t = 0; t < 3; ++t) acc[st][t] = (f32x4){0.f, 0.f, 0.f, 0.f};

    for (int kc = 0; kc < 24; ++kc) {
        short8 af0 = *(const short8*)&xs[m][kc * 32 + g * 8];
        short8 af1 = *(const short8*)&xs[16 + m][kc * 32 + g * 8];
        #pragma unroll
        for (int tt = 0; tt < 3; ++tt) {
            int nc = w * 3 + tt;
            short8 bfrg = *(const short8*)(wF + (size_t)(nc * 24 + kc) * 512 + lane * 8);
            acc[0][tt] = __builtin_amdgcn_mfma_f32_16x16x32_bf16(af0, bfrg, acc[0][tt], 0, 0, 0);
            acc[1][tt] = __builtin_amdgcn_mfma_f32_16x16x32_bf16(af1, bfrg, acc[1][tt], 0, 0, 0);
        }
    }

    int b2 = r0 >> 12;
    int s = (r0 & 4095) >> 5;
    #pragma unroll
    for (int st = 0; st < 2; ++st) {
        #pragma unroll
        for (int tt = 0; tt < 3; ++tt) {
            int nc = w * 3 + tt;
            int o = nc >> 2;
            int t = nc & 3;
            const float* bias_p = (o == 0) ? bq : (o == 1) ? bk : bv;
            float bias = bias_p[t * 16 + m];
            #pragma unroll
            for (int r = 0; r < 4; ++r) {
                float val = acc[st][tt][r] + bias;
                if (o == 0) val *= QSCALE;
                tr[w][g * 4 + r][m] = f2bf(val);
            }
            if (o < 2) {
                if (g < 2) {
                    short8 v8;
                    #pragma unroll
                    for (int j = 0; j < 8; ++j) v8[j] = (short)tr[w][m][g * 8 + j];
                    unsigned short* dst = (o == 0) ? Qf : Kf;
                    int c = t >> 1;
                    *(short8*)&dst[(size_t)((blockIdx.x * 2 + st) * 2 + c) * 512
                                   + (((t & 1) * 2 + g) * 16 + m) * 8] = v8;
                }
            } else {
                if (g < 2) {
                    short8 v8;
                    #pragma unroll
                    for (int j = 0; j < 8; ++j) v8[j] = (short)tr[w][g * 8 + j][m];
                    *(short8*)&Vf[((size_t)(b2 * 128 + s) * 4 + t) * 512
                                  + ((st * 2 + g) * 16 + m) * 8] = v8;
                }
            }
        }
    }
}

// ---------------------------------------------------------------------------
// Kernel 2 (v12): swapped-QK + PACKED P_T LDS (3 LDS ops/tile, was 10
// bpermutes) + ROW-SUM VIA ONES-A MFMA (matrix pipe, ~5% busy).
// Theory: per-CU LDS pipe is the shared serializer (explains rounds 5-16
// nulls: VALU cut, L2 pinning, TLP, pipelining never reduced LDS op count).
// lane (m,g) holds P[kv=g*4+r][q=m] per tt -> 4 consecutive kv pack into
// one b64 write; PV B-frag = one b128 read of PT[m][g*8..+7]. Same-wave
// write->read: lgkmcnt only, no barrier. l = mfma(onesA, P) -> every lane
// gets sum_kv P[kv][m] in matching layout, rescales with acc.
// Keeps: pairing, in-place K/V rotation, (512,2).
// ---------------------------------------------------------------------------
__global__ void __launch_bounds__(512, 2) attn_kernel(
        const unsigned short* __restrict__ Qf,
        const unsigned short* __restrict__ Kf,
        const unsigned short* __restrict__ Vf,
        float* __restrict__ out) {
    __shared__ __align__(16) unsigned short PT[8][16][40];   // 10 KB, pitch 80B
    __shared__ __align__(16) unsigned short pacc[8][16][68];
    __shared__ float pm[8][16];
    __shared__ float pl[8][16];

    int j = blockIdx.x;
    int b = j & 3;
    int qt = j >> 2;                       // 0..127
    int base0 = qt * 16;
    int base1 = (255 - qt) * 16;
    int ns0 = (qt + 2) >> 1;
    int ns1 = (257 - qt) >> 1;
    int tid = threadIdx.x;
    int w = tid >> 6;
    int lane = tid & 63;
    int m = lane & 15, g = lane >> 4;

    const unsigned short* Q0 = Qf + (size_t)(b * 256 + qt) * 1024 + lane * 8;
    const unsigned short* Q1 = Qf + (size_t)(b * 256 + 255 - qt) * 1024 + lane * 8;
    short8 qf00 = *(const short8*)(Q0);
    short8 qf01 = *(const short8*)(Q0 + 512);
    short8 qf10 = *(const short8*)(Q1);
    short8 qf11 = *(const short8*)(Q1 + 512);

    short8 onesA;
    #pragma unroll
    for (int jj = 0; jj < 8; ++jj) onesA[jj] = (short)0x3F80;   // bf16(1.0) all lanes

    f32x4 acc[2][5];                       // [rt][0..3]=O^T tiles, [4]=l via ones
    #pragma unroll
    for (int rt = 0; rt < 2; ++rt)
        #pragma unroll
        for (int t = 0; t < 5; ++t) acc[rt][t] = (f32x4){0.f, 0.f, 0.f, 0.f};
    float mrun0 = -INFINITY, mrun1 = -INFINITY;

    const unsigned short* Kbase = Kf + (size_t)(b * 256) * 1024 + lane * 8;
    const unsigned short* Vbase = Vf + (size_t)(b * 128) * 2048 + lane * 8;

    short8 kf[4], vf[4];
    if (w < ns1) {
        #pragma unroll
        for (int t = 0; t < 4; ++t) {
            kf[t] = *(const short8*)(Kbase + (size_t)w * 2048 + t * 512);
            vf[t] = *(const short8*)(Vbase + (size_t)w * 2048 + t * 512);
        }
    }

    for (int s = w; s < ns1; s += 8) {
        int kv0 = s * 32;
        int sn = s + 8;
        bool have = (sn < ns1);
        bool do0 = (s < ns0);

        // ================= rt0 (shallow tile) =================
        if (do0) {
            f32x4 st0 = (f32x4){0.f, 0.f, 0.f, 0.f};
            f32x4 st1 = (f32x4){0.f, 0.f, 0.f, 0.f};
            st0 = __builtin_amdgcn_mfma_f32_16x16x32_bf16(kf[0], qf00, st0, 0, 0, 0);
            st0 = __builtin_amdgcn_mfma_f32_16x16x32_bf16(kf[1], qf01, st0, 0, 0, 0);
            st1 = __builtin_amdgcn_mfma_f32_16x16x32_bf16(kf[2], qf00, st1, 0, 0, 0);
            st1 = __builtin_amdgcn_mfma_f32_16x16x32_bf16(kf[3], qf01, st1, 0, 0, 0);
            if (s == ns0 - 1) {
                int q = base0 + m;
                #pragma unroll
                for (int r = 0; r < 4; ++r) {
                    if (kv0 + g * 4 + r > q)      st0[r] = -INFINITY;
                    if (kv0 + 16 + g * 4 + r > q) st1[r] = -INFINITY;
                }
            }
            float th = mrun0 + 8.0f;
            bool need = (st0[0] > th) | (st0[1] > th) | (st0[2] > th) | (st0[3] > th)
                      | (st1[0] > th) | (st1[1] > th) | (st1[2] > th) | (st1[3] > th);
            if (__any(need)) {
                float rmax = fmaxf(fmaxf(fmaxf(st0[0], st0[1]), fmaxf(st0[2], st0[3])),
                                   fmaxf(fmaxf(st1[0], st1[1]), fmaxf(st1[2], st1[3])));
                rmax = fmaxf(rmax, __shfl_xor(rmax, 16));
                rmax = fmaxf(rmax, __shfl_xor(rmax, 32));
                float mnew = fmaxf(mrun0, rmax);
                float alpha = __builtin_amdgcn_exp2f(mrun0 - mnew);
                mrun0 = mnew;
                #pragma unroll
                for (int t = 0; t < 5; ++t)
                    #pragma unroll
                    for (int r = 0; r < 4; ++r) acc[0][t][r] *= alpha;
            }
            float p00 = __builtin_amdgcn_exp2f(st0[0] - mrun0);
            float p01 = __builtin_amdgcn_exp2f(st0[1] - mrun0);
            float p02 = __builtin_amdgcn_exp2f(st0[2] - mrun0);
            float p03 = __builtin_amdgcn_exp2f(st0[3] - mrun0);
            float p10 = __builtin_amdgcn_exp2f(st1[0] - mrun0);
            float p11 = __builtin_amdgcn_exp2f(st1[1] - mrun0);
            float p12 = __builtin_amdgcn_exp2f(st1[2] - mrun0);
            float p13 = __builtin_amdgcn_exp2f(st1[3] - mrun0);
            // packed P_T write: 2 x ds_write_b64 (kv g*4.. consecutive)
            *(uint2v*)&PT[w][m][g * 4]      = (uint2v){packbf(p00, p01), packbf(p02, p03)};
            *(uint2v*)&PT[w][m][16 + g * 4] = (uint2v){packbf(p10, p11), packbf(p12, p13)};
            // PV B-frag: 1 x ds_read_b128 (same-wave dep, lgkmcnt only)
            short8 pb = *(const short8*)&PT[w][m][g * 8];
            #pragma unroll
            for (int t = 0; t < 4; ++t)
                acc[0][t] = __builtin_amdgcn_mfma_f32_16x16x32_bf16(vf[t], pb, acc[0][t], 0, 0, 0);
            acc[0][4] = __builtin_amdgcn_mfma_f32_16x16x32_bf16(onesA, pb, acc[0][4], 0, 0, 0);
        }

        // ================= rt1 (deep tile) =================
        {
            f32x4 st0 = (f32x4){0.f, 0.f, 0.f, 0.f};
            f32x4 st1 = (f32x4){0.f, 0.f, 0.f, 0.f};
            st0 = __builtin_amdgcn_mfma_f32_16x16x32_bf16(kf[0], qf10, st0, 0, 0, 0);
            st0 = __builtin_amdgcn_mfma_f32_16x16x32_bf16(kf[1], qf11, st0, 0, 0, 0);
            st1 = __builtin_amdgcn_mfma_f32_16x16x32_bf16(kf[2], qf10, st1, 0, 0, 0);
            st1 = __builtin_amdgcn_mfma_f32_16x16x32_bf16(kf[3], qf11, st1, 0, 0, 0);

            // kf last read above -> in-place reload for s+8
            if (have) {
                #pragma unroll
                for (int t = 0; t < 4; ++t)
                    kf[t] = *(const short8*)(Kbase + (size_t)sn * 2048 + t * 512);
            }

            if (s == ns1 - 1) {
                int q = base1 + m;
                #pragma unroll
                for (int r = 0; r < 4; ++r) {
                    if (kv0 + g * 4 + r > q)      st0[r] = -INFINITY;
                    if (kv0 + 16 + g * 4 + r > q) st1[r] = -INFINITY;
                }
            }
            float th = mrun1 + 8.0f;
            bool need = (st0[0] > th) | (st0[1] > th) | (st0[2] > th) | (st0[3] > th)
                      | (st1[0] > th) | (st1[1] > th) | (st1[2] > th) | (st1[3] > th);
            if (__any(need)) {
                float rmax = fmaxf(fmaxf(fmaxf(st0[0], st0[1]), fmaxf(st0[2], st0[3])),
                                   fmaxf(fmaxf(st1[0], st1[1]), fmaxf(st1[2], st1[3])));
                rmax = fmaxf(rmax, __shfl_xor(rmax, 16));
                rmax = fmaxf(rmax, __shfl_xor(rmax, 32));
                float mnew = fmaxf(mrun1, rmax);
                float alpha = __builtin_amdgcn_exp2f(mrun1 - mnew);
                mrun1 = mnew;
                #pragma unroll
                for (int t = 0; t < 5; ++t)
                    #pragma unroll
                    for (int r = 0; r < 4; ++r) acc[1][t][r] *= alpha;
            }
            float p00 = __builtin_amdgcn_exp2f(st0[0] - mrun1);
            float p01 = __builtin_amdgcn_exp2f(st0[1] - mrun1);
            float p02 = __builtin_amdgcn_exp2f(st0[2] - mrun1);
            float p03 = __builtin_amdgcn_exp2f(st0[3] - mrun1);
            float p10 = __builtin_amdgcn_exp2f(st1[0] - mrun1);
            float p11 = __builtin_amdgcn_exp2f(st1[1] - mrun1);
            float p12 = __builtin_amdgcn_exp2f(st1[2] - mrun1);
            float p13 = __builtin_amdgcn_exp2f(st1[3] - mrun1);
            *(uint2v*)&PT[w][m][g * 4]      = (uint2v){packbf(p00, p01), packbf(p02, p03)};
            *(uint2v*)&PT[w][m][16 + g * 4] = (uint2v){packbf(p10, p11), packbf(p12, p13)};
            short8 pb = *(const short8*)&PT[w][m][g * 8];
            #pragma unroll
            for (int t = 0; t < 4; ++t)
                acc[1][t] = __builtin_amdgcn_mfma_f32_16x16x32_bf16(vf[t], pb, acc[1][t], 0, 0, 0);
            acc[1][4] = __builtin_amdgcn_mfma_f32_16x16x32_bf16(onesA, pb, acc[1][4], 0, 0, 0);

            // vf last read above -> in-place reload for s+8
            if (have) {
                #pragma unroll
                for (int t = 0; t < 4; ++t)
                    vf[t] = *(const short8*)(Vbase + (size_t)sn * 2048 + t * 512);
            }
        }
    }

    // ===== per-wave partials + combine (acc = O^T[d][q=m], l = acc[rt][4][0]) =====
    #pragma unroll
    for (int rt = 0; rt < 2; ++rt) {
        int qbase = (rt == 0) ? base0 : base1;
        float mr = (rt == 0) ? mrun0 : mrun1;
        if (lane < 16) {          // g == 0: one writer per q
            pm[w][m] = mr;
            pl[w][m] = acc[rt][4][0];
        }
        #pragma unroll
        for (int t = 0; t < 4; ++t)
            #pragma unroll
            for (int r = 0; r < 4; ++r)
                pacc[w][m][t * 16 + g * 4 + r] = f2bf(acc[rt][t][r]);
        __syncthreads();

        if (tid < 256) {
            int row = tid >> 4;
            int c4 = (tid & 15) * 4;
            float mmax = pm[0][row];
            #pragma unroll
            for (int w2 = 1; w2 < 8; ++w2) mmax = fmaxf(mmax, pm[w2][row]);
            float lt = 0.f;
            float o0 = 0.f, o1 = 0.f, o2 = 0.f, o3 = 0.f;
            #pragma unroll
            for (int w2 = 0; w2 < 8; ++w2) {
                float sc2 = __builtin_amdgcn_exp2f(pm[w2][row] - mmax);
                lt += pl[w2][row] * sc2;
                short4v pa4 = *(const short4v*)&pacc[w2][row][c4];
                o0 += bf2f((unsigned short)pa4[0]) * sc2;
                o1 += bf2f((unsigned short)pa4[1]) * sc2;
                o2 += bf2f((unsigned short)pa4[2]) * sc2;
                o3 += bf2f((unsigned short)pa4[3]) * sc2;
            }
            float invl = 1.0f / lt;
            float4 res = make_float4(o0 * invl, o1 * invl, o2 * invl, o3 * invl);
            *(float4*)&out[(size_t)(b * SEQ + qbase + row) * DOUT + c4] = res;
        }
        __syncthreads();
    }
}

// ---------------------------------------------------------------------------
extern "C" void kernel_launch(void* const* d_in, const int* in_sizes, int n_in,
                              void* d_out, int out_size, void* d_ws, size_t ws_size,
                              hipStream_t stream) {
    const float* x  = (const float*)d_in[0];
    const float* wq = (const float*)d_in[1];
    const float* bq = (const float*)d_in[2];
    const float* wk = (const float*)d_in[3];
    const float* bk = (const float*)d_in[4];
    const float* wv = (const float*)d_in[5];
    const float* bv = (const float*)d_in[6];
    float* out = (float*)d_out;

    char* ws = (char*)d_ws;
    unsigned short* wF = (unsigned short*)ws;                       // 294912 B
    unsigned short* Qf = (unsigned short*)(ws + 294912);            // 2 MB
    unsigned short* Kf = (unsigned short*)(ws + 294912 + 2097152);  // 2 MB
    unsigned short* Vf = (unsigned short*)(ws + 294912 + 4194304);  // 2 MB

    wprep_kernel<<<36, 256, 0, stream>>>(wq, wk, wv, wF);
    proj_kernel<<<512, 256, 0, stream>>>(x, bq, bk, bv, wF, Qf, Kf, Vf);
    attn_kernel<<<512, 512, 0, stream>>>(Qf, Kf, Vf, out);
}

// Round 19
// 48.724 us; speedup vs baseline: 1.1668x; 1.0083x over previous
//
#include <hip/hip_runtime.h>
#include <hip/hip_bf16.h>

#define BATCH 4
#define SEQ   4096
#define DIN   768
#define DOUT  64

typedef __attribute__((ext_vector_type(4))) float f32x4;
typedef __attribute__((ext_vector_type(8))) short short8;
typedef __attribute__((ext_vector_type(4))) short short4v;
typedef __attribute__((ext_vector_type(2))) unsigned uint2v;

#define QSCALE 0.18033688011112043f  /* 0.125 * log2(e) */

static __device__ __forceinline__ unsigned short f2bf(float f) {
    union { float f; unsigned u; } un; un.f = f;
    unsigned r = un.u + 0x7FFF + ((un.u >> 16) & 1);
    return (unsigned short)(r >> 16);
}
static __device__ __forceinline__ float bf2f(unsigned short h) {
    union { unsigned u; float f; } un; un.u = ((unsigned)h) << 16;
    return un.f;
}
static __device__ __forceinline__ unsigned packbf(float lo, float hi) {
    return ((unsigned)f2bf(hi) << 16) | (unsigned)f2bf(lo);
}

// ---------------------------------------------------------------------------
// Kernel 0 (v2, unchanged): weights -> B-fragment order.
// ---------------------------------------------------------------------------
__global__ void wprep_kernel(const float* __restrict__ wq,
                             const float* __restrict__ wk,
                             const float* __restrict__ wv,
                             unsigned short* __restrict__ wF) {
    __shared__ float lds[64][65];
    int o = blockIdx.x / 12, kt = blockIdx.x % 12;
    const float* w = (o == 0) ? wq : (o == 1) ? wk : wv;
    int tid = threadIdx.x;
    int k0 = kt * 64;
    #pragma unroll
    for (int i = 0; i < 16; ++i) {
        int flat = tid + i * 256;
        int kl = flat >> 6, n = flat & 63;
        lds[kl][n] = w[(k0 + kl) * 64 + n];
    }
    __syncthreads();
    int lane = tid & 63;
    int m = lane & 15, g = lane >> 4;
    #pragma unroll
    for (int i = 0; i < 2; ++i) {
        int f = i * 4 + (tid >> 6);
        int t = f >> 1, kcl = f & 1;
        int kc = kt * 2 + kcl;
        int nc = o * 4 + t;
        short8 v;
        #pragma unroll
        for (int j = 0; j < 8; ++j)
            v[j] = (short)f2bf(lds[kcl * 32 + g * 8 + j][t * 16 + m]);
        *(short8*)&wF[(size_t)(nc * 24 + kc) * 512 + lane * 8] = v;
    }
}

// ---------------------------------------------------------------------------
// Kernel 1 (v9): QKV projection with IN-PLACE ROTATED wF/af PREFETCH.
// v8's inner loop (3 wF L2-loads -> 6 MFMAs, ~60 VGPR) serialized each
// chunk behind its loads (round-8/14 signature). Now chunk kc+1's wF frags
// and af LDS reads are issued BEFORE kc's MFMAs consume the current regs,
// rotating at loop bottom. ~110 VGPR; LDS 48.5KB -> still 3 blocks/CU.
// Everything else (staging, epilogue, layouts) identical to v8.
// ---------------------------------------------------------------------------
__global__ void __launch_bounds__(256) proj_kernel(
        const float* __restrict__ x,
        const float* __restrict__ bq,
        const float* __restrict__ bk,
        const float* __restrict__ bv,
        const unsigned short* __restrict__ wF,
        unsigned short* __restrict__ Qf,
        unsigned short* __restrict__ Kf,
        unsigned short* __restrict__ Vf) {
    __shared__ __align__(16) unsigned short xs[32][776];   // 48.5 KB
    __shared__ unsigned short tr[4][16][24];               // 3 KB

    int tid = threadIdx.x;
    int w = tid >> 6;
    int lane = tid & 63;
    int m = lane & 15, g = lane >> 4;
    int r0 = blockIdx.x * 32;

    {
        const float* xbase = x + (size_t)r0 * DIN;
        #pragma unroll
        for (int i = 0; i < 24; ++i) {
            int flat4 = tid + i * 256;
            int row = flat4 / 192;
            int c4 = flat4 - row * 192;
            float4 v = *(const float4*)(xbase + (size_t)row * DIN + c4 * 4);
            short4v sv;
            sv[0] = (short)f2bf(v.x); sv[1] = (short)f2bf(v.y);
            sv[2] = (short)f2bf(v.z); sv[3] = (short)f2bf(v.w);
            *(short4v*)&xs[row][c4 * 4] = sv;
        }
    }
    __syncthreads();

    f32x4 acc[2][3];
    #pragma unroll
    for (int st = 0; st < 2; ++st)
        #pragma unroll
        for (int t = 0; t < 3; ++t) acc[st][t] = (f32x4){0.f, 0.f, 0.f, 0.f};

    // wF base for this wave's 3 column-tiles (contiguous 1KB frags, +1KB/chunk)
    const unsigned short* wb0 = wF + (size_t)((w * 3 + 0) * 24) * 512 + lane * 8;
    const unsigned short* wb1 = wF + (size_t)((w * 3 + 1) * 24) * 512 + lane * 8;
    const unsigned short* wb2 = wF + (size_t)((w * 3 + 2) * 24) * 512 + lane * 8;

    // preload chunk 0
    short8 bf0 = *(const short8*)(wb0);
    short8 bf1 = *(const short8*)(wb1);
    short8 bf2 = *(const short8*)(wb2);
    short8 af0 = *(const short8*)&xs[m][g * 8];
    short8 af1 = *(const short8*)&xs[16 + m][g * 8];

    for (int kc = 0; kc < 24; ++kc) {
        // issue next chunk's loads BEFORE consuming current regs
        short8 nb0, nb1, nb2, na0, na1;
        bool have = (kc + 1) < 24;
        if (have) {
            int off = (kc + 1) * 512;
            nb0 = *(const short8*)(wb0 + off);
            nb1 = *(const short8*)(wb1 + off);
            nb2 = *(const short8*)(wb2 + off);
            na0 = *(const short8*)&xs[m][(kc + 1) * 32 + g * 8];
            na1 = *(const short8*)&xs[16 + m][(kc + 1) * 32 + g * 8];
        }
        acc[0][0] = __builtin_amdgcn_mfma_f32_16x16x32_bf16(af0, bf0, acc[0][0], 0, 0, 0);
        acc[1][0] = __builtin_amdgcn_mfma_f32_16x16x32_bf16(af1, bf0, acc[1][0], 0, 0, 0);
        acc[0][1] = __builtin_amdgcn_mfma_f32_16x16x32_bf16(af0, bf1, acc[0][1], 0, 0, 0);
        acc[1][1] = __builtin_amdgcn_mfma_f32_16x16x32_bf16(af1, bf1, acc[1][1], 0, 0, 0);
        acc[0][2] = __builtin_amdgcn_mfma_f32_16x16x32_bf16(af0, bf2, acc[0][2], 0, 0, 0);
        acc[1][2] = __builtin_amdgcn_mfma_f32_16x16x32_bf16(af1, bf2, acc[1][2], 0, 0, 0);
        if (have) {
            bf0 = nb0; bf1 = nb1; bf2 = nb2;
            af0 = na0; af1 = na1;
        }
    }

    int b2 = r0 >> 12;
    int s = (r0 & 4095) >> 5;
    #pragma unroll
    for (int st = 0; st < 2; ++st) {
        #pragma unroll
        for (int tt = 0; tt < 3; ++tt) {
            int nc = w * 3 + tt;
            int o = nc >> 2;
            int t = nc & 3;
            const float* bias_p = (o == 0) ? bq : (o == 1) ? bk : bv;
            float bias = bias_p[t * 16 + m];
            #pragma unroll
            for (int r = 0; r < 4; ++r) {
                float val = acc[st][tt][r] + bias;
                if (o == 0) val *= QSCALE;
                tr[w][g * 4 + r][m] = f2bf(val);
            }
            if (o < 2) {
                if (g < 2) {
                    short8 v8;
                    #pragma unroll
                    for (int j = 0; j < 8; ++j) v8[j] = (short)tr[w][m][g * 8 + j];
                    unsigned short* dst = (o == 0) ? Qf : Kf;
                    int c = t >> 1;
                    *(short8*)&dst[(size_t)((blockIdx.x * 2 + st) * 2 + c) * 512
                                   + (((t & 1) * 2 + g) * 16 + m) * 8] = v8;
                }
            } else {
                if (g < 2) {
                    short8 v8;
                    #pragma unroll
                    for (int j = 0; j < 8; ++j) v8[j] = (short)tr[w][g * 8 + j][m];
                    *(short8*)&Vf[((size_t)(b2 * 128 + s) * 4 + t) * 512
                                  + ((st * 2 + g) * 16 + m) * 8] = v8;
                }
            }
        }
    }
}

// ---------------------------------------------------------------------------
// Kernel 2 (v12, unchanged): swapped-QK + packed P_T LDS + ones-A row-sum.
// ---------------------------------------------------------------------------
__global__ void __launch_bounds__(512, 2) attn_kernel(
        const unsigned short* __restrict__ Qf,
        const unsigned short* __restrict__ Kf,
        const unsigned short* __restrict__ Vf,
        float* __restrict__ out) {
    __shared__ __align__(16) unsigned short PT[8][16][40];
    __shared__ __align__(16) unsigned short pacc[8][16][68];
    __shared__ float pm[8][16];
    __shared__ float pl[8][16];

    int j = blockIdx.x;
    int b = j & 3;
    int qt = j >> 2;
    int base0 = qt * 16;
    int base1 = (255 - qt) * 16;
    int ns0 = (qt + 2) >> 1;
    int ns1 = (257 - qt) >> 1;
    int tid = threadIdx.x;
    int w = tid >> 6;
    int lane = tid & 63;
    int m = lane & 15, g = lane >> 4;

    const unsigned short* Q0 = Qf + (size_t)(b * 256 + qt) * 1024 + lane * 8;
    const unsigned short* Q1 = Qf + (size_t)(b * 256 + 255 - qt) * 1024 + lane * 8;
    short8 qf00 = *(const short8*)(Q0);
    short8 qf01 = *(const short8*)(Q0 + 512);
    short8 qf10 = *(const short8*)(Q1);
    short8 qf11 = *(const short8*)(Q1 + 512);

    short8 onesA;
    #pragma unroll
    for (int jj = 0; jj < 8; ++jj) onesA[jj] = (short)0x3F80;

    f32x4 acc[2][5];
    #pragma unroll
    for (int rt = 0; rt < 2; ++rt)
        #pragma unroll
        for (int t = 0; t < 5; ++t) acc[rt][t] = (f32x4){0.f, 0.f, 0.f, 0.f};
    float mrun0 = -INFINITY, mrun1 = -INFINITY;

    const unsigned short* Kbase = Kf + (size_t)(b * 256) * 1024 + lane * 8;
    const unsigned short* Vbase = Vf + (size_t)(b * 128) * 2048 + lane * 8;

    short8 kf[4], vf[4];
    if (w < ns1) {
        #pragma unroll
        for (int t = 0; t < 4; ++t) {
            kf[t] = *(const short8*)(Kbase + (size_t)w * 2048 + t * 512);
            vf[t] = *(const short8*)(Vbase + (size_t)w * 2048 + t * 512);
        }
    }

    for (int s = w; s < ns1; s += 8) {
        int kv0 = s * 32;
        int sn = s + 8;
        bool have = (sn < ns1);
        bool do0 = (s < ns0);

        if (do0) {
            f32x4 st0 = (f32x4){0.f, 0.f, 0.f, 0.f};
            f32x4 st1 = (f32x4){0.f, 0.f, 0.f, 0.f};
            st0 = __builtin_amdgcn_mfma_f32_16x16x32_bf16(kf[0], qf00, st0, 0, 0, 0);
            st0 = __builtin_amdgcn_mfma_f32_16x16x32_bf16(kf[1], qf01, st0, 0, 0, 0);
            st1 = __builtin_amdgcn_mfma_f32_16x16x32_bf16(kf[2], qf00, st1, 0, 0, 0);
            st1 = __builtin_amdgcn_mfma_f32_16x16x32_bf16(kf[3], qf01, st1, 0, 0, 0);
            if (s == ns0 - 1) {
                int q = base0 + m;
                #pragma unroll
                for (int r = 0; r < 4; ++r) {
                    if (kv0 + g * 4 + r > q)      st0[r] = -INFINITY;
                    if (kv0 + 16 + g * 4 + r > q) st1[r] = -INFINITY;
                }
            }
            float th = mrun0 + 8.0f;
            bool need = (st0[0] > th) | (st0[1] > th) | (st0[2] > th) | (st0[3] > th)
                      | (st1[0] > th) | (st1[1] > th) | (st1[2] > th) | (st1[3] > th);
            if (__any(need)) {
                float rmax = fmaxf(fmaxf(fmaxf(st0[0], st0[1]), fmaxf(st0[2], st0[3])),
                                   fmaxf(fmaxf(st1[0], st1[1]), fmaxf(st1[2], st1[3])));
                rmax = fmaxf(rmax, __shfl_xor(rmax, 16));
                rmax = fmaxf(rmax, __shfl_xor(rmax, 32));
                float mnew = fmaxf(mrun0, rmax);
                float alpha = __builtin_amdgcn_exp2f(mrun0 - mnew);
                mrun0 = mnew;
                #pragma unroll
                for (int t = 0; t < 5; ++t)
                    #pragma unroll
                    for (int r = 0; r < 4; ++r) acc[0][t][r] *= alpha;
            }
            float p00 = __builtin_amdgcn_exp2f(st0[0] - mrun0);
            float p01 = __builtin_amdgcn_exp2f(st0[1] - mrun0);
            float p02 = __builtin_amdgcn_exp2f(st0[2] - mrun0);
            float p03 = __builtin_amdgcn_exp2f(st0[3] - mrun0);
            float p10 = __builtin_amdgcn_exp2f(st1[0] - mrun0);
            float p11 = __builtin_amdgcn_exp2f(st1[1] - mrun0);
            float p12 = __builtin_amdgcn_exp2f(st1[2] - mrun0);
            float p13 = __builtin_amdgcn_exp2f(st1[3] - mrun0);
            *(uint2v*)&PT[w][m][g * 4]      = (uint2v){packbf(p00, p01), packbf(p02, p03)};
            *(uint2v*)&PT[w][m][16 + g * 4] = (uint2v){packbf(p10, p11), packbf(p12, p13)};
            short8 pb = *(const short8*)&PT[w][m][g * 8];
            #pragma unroll
            for (int t = 0; t < 4; ++t)
                acc[0][t] = __builtin_amdgcn_mfma_f32_16x16x32_bf16(vf[t], pb, acc[0][t], 0, 0, 0);
            acc[0][4] = __builtin_amdgcn_mfma_f32_16x16x32_bf16(onesA, pb, acc[0][4], 0, 0, 0);
        }

        {
            f32x4 st0 = (f32x4){0.f, 0.f, 0.f, 0.f};
            f32x4 st1 = (f32x4){0.f, 0.f, 0.f, 0.f};
            st0 = __builtin_amdgcn_mfma_f32_16x16x32_bf16(kf[0], qf10, st0, 0, 0, 0);
            st0 = __builtin_amdgcn_mfma_f32_16x16x32_bf16(kf[1], qf11, st0, 0, 0, 0);
            st1 = __builtin_amdgcn_mfma_f32_16x16x32_bf16(kf[2], qf10, st1, 0, 0, 0);
            st1 = __builtin_amdgcn_mfma_f32_16x16x32_bf16(kf[3], qf11, st1, 0, 0, 0);

            if (have) {
                #pragma unroll
                for (int t = 0; t < 4; ++t)
                    kf[t] = *(const short8*)(Kbase + (size_t)sn * 2048 + t * 512);
            }

            if (s == ns1 - 1) {
                int q = base1 + m;
                #pragma unroll
                for (int r = 0; r < 4; ++r) {
                    if (kv0 + g * 4 + r > q)      st0[r] = -INFINITY;
                    if (kv0 + 16 + g * 4 + r > q) st1[r] = -INFINITY;
                }
            }
            float th = mrun1 + 8.0f;
            bool need = (st0[0] > th) | (st0[1] > th) | (st0[2] > th) | (st0[3] > th)
                      | (st1[0] > th) | (st1[1] > th) | (st1[2] > th) | (st1[3] > th);
            if (__any(need)) {
                float rmax = fmaxf(fmaxf(fmaxf(st0[0], st0[1]), fmaxf(st0[2], st0[3])),
                                   fmaxf(fmaxf(st1[0], st1[1]), fmaxf(st1[2], st1[3])));
                rmax = fmaxf(rmax, __shfl_xor(rmax, 16));
                rmax = fmaxf(rmax, __shfl_xor(rmax, 32));
                float mnew = fmaxf(mrun1, rmax);
                float alpha = __builtin_amdgcn_exp2f(mrun1 - mnew);
                mrun1 = mnew;
                #pragma unroll
                for (int t = 0; t < 5; ++t)
                    #pragma unroll
                    for (int r = 0; r < 4; ++r) acc[1][t][r] *= alpha;
            }
            float p00 = __builtin_amdgcn_exp2f(st0[0] - mrun1);
            float p01 = __builtin_amdgcn_exp2f(st0[1] - mrun1);
            float p02 = __builtin_amdgcn_exp2f(st0[2] - mrun1);
            float p03 = __builtin_amdgcn_exp2f(st0[3] - mrun1);
            float p10 = __builtin_amdgcn_exp2f(st1[0] - mrun1);
            float p11 = __builtin_amdgcn_exp2f(st1[1] - mrun1);
            float p12 = __builtin_amdgcn_exp2f(st1[2] - mrun1);
            float p13 = __builtin_amdgcn_exp2f(st1[3] - mrun1);
            *(uint2v*)&PT[w][m][g * 4]      = (uint2v){packbf(p00, p01), packbf(p02, p03)};
            *(uint2v*)&PT[w][m][16 + g * 4] = (uint2v){packbf(p10, p11), packbf(p12, p13)};
            short8 pb = *(const short8*)&PT[w][m][g * 8];
            #pragma unroll
            for (int t = 0; t < 4; ++t)
                acc[1][t] = __builtin_amdgcn_mfma_f32_16x16x32_bf16(vf[t], pb, acc[1][t], 0, 0, 0);
            acc[1][4] = __builtin_amdgcn_mfma_f32_16x16x32_bf16(onesA, pb, acc[1][4], 0, 0, 0);

            if (have) {
                #pragma unroll
                for (int t = 0; t < 4; ++t)
                    vf[t] = *(const short8*)(Vbase + (size_t)sn * 2048 + t * 512);
            }
        }
    }

    #pragma unroll
    for (int rt = 0; rt < 2; ++rt) {
        int qbase = (rt == 0) ? base0 : base1;
        float mr = (rt == 0) ? mrun0 : mrun1;
        if (lane < 16) {
            pm[w][m] = mr;
            pl[w][m] = acc[rt][4][0];
        }
        #pragma unroll
        for (int t = 0; t < 4; ++t)
            #pragma unroll
            for (int r = 0; r < 4; ++r)
                pacc[w][m][t * 16 + g * 4 + r] = f2bf(acc[rt][t][r]);
        __syncthreads();

        if (tid < 256) {
            int row = tid >> 4;
            int c4 = (tid & 15) * 4;
            float mmax = pm[0][row];
            #pragma unroll
            for (int w2 = 1; w2 < 8; ++w2) mmax = fmaxf(mmax, pm[w2][row]);
            float lt = 0.f;
            float o0 = 0.f, o1 = 0.f, o2 = 0.f, o3 = 0.f;
            #pragma unroll
            for (int w2 = 0; w2 < 8; ++w2) {
                float sc2 = __builtin_amdgcn_exp2f(pm[w2][row] - mmax);
                lt += pl[w2][row] * sc2;
                short4v pa4 = *(const short4v*)&pacc[w2][row][c4];
                o0 += bf2f((unsigned short)pa4[0]) * sc2;
                o1 += bf2f((unsigned short)pa4[1]) * sc2;
                o2 += bf2f((unsigned short)pa4[2]) * sc2;
                o3 += bf2f((unsigned short)pa4[3]) * sc2;
            }
            float invl = 1.0f / lt;
            float4 res = make_float4(o0 * invl, o1 * invl, o2 * invl, o3 * invl);
            *(float4*)&out[(size_t)(b * SEQ + qbase + row) * DOUT + c4] = res;
        }
        __syncthreads();
    }
}

// ---------------------------------------------------------------------------
extern "C" void kernel_launch(void* const* d_in, const int* in_sizes, int n_in,
                              void* d_out, int out_size, void* d_ws, size_t ws_size,
                              hipStream_t stream) {
    const float* x  = (const float*)d_in[0];
    const float* wq = (const float*)d_in[1];
    const float* bq = (const float*)d_in[2];
    const float* wk = (const float*)d_in[3];
    const float* bk = (const float*)d_in[4];
    const float* wv = (const float*)d_in[5];
    const float* bv = (const float*)d_in[6];
    float* out = (float*)d_out;

    char* ws = (char*)d_ws;
    unsigned short* wF = (unsigned short*)ws;                       // 294912 B
    unsigned short* Qf = (unsigned short*)(ws + 294912);            // 2 MB
    unsigned short* Kf = (unsigned short*)(ws + 294912 + 2097152);  // 2 MB
    unsigned short* Vf = (unsigned short*)(ws + 294912 + 4194304);  // 2 MB

    wprep_kernel<<<36, 256, 0, stream>>>(wq, wk, wv, wF);
    proj_kernel<<<512, 256, 0, stream>>>(x, bq, bk, bv, wF, Qf, Kf, Vf);
    attn_kernel<<<512, 512, 0, stream>>>(Qf, Kf, Vf, out);
}